// Round 15
// baseline (380.815 us; speedup 1.0000x reference)
//
#include <hip/hip_runtime.h>
#include <hip/hip_bf16.h>
#include <math.h>

typedef __attribute__((ext_vector_type(8))) short short8;
typedef __attribute__((ext_vector_type(4))) float floatx4;

__device__ __forceinline__ float bf2f(unsigned short u) {
  union { unsigned int i; float f; } v; v.i = ((unsigned int)u) << 16; return v.f;
}
__device__ __forceinline__ unsigned short f2bf(float f) {
  union { float f; unsigned int u; } v; v.f = f;
  unsigned int r = (v.u + 0x7fffu + ((v.u >> 16) & 1u)) >> 16;
  return (unsigned short)r;
}
__device__ __forceinline__ int imin(int a, int b) { return a < b ? a : b; }
__device__ __forceinline__ int iclamp(int v, int lo, int hi) {
  return v < lo ? lo : (v > hi ? hi : v);
}
__device__ __forceinline__ float uasf(unsigned int u) {
  union { unsigned int i; float f; } v; v.i = u; return v.f;
}
// 16-lane ring-rotation sum via DPP (pure VALU)
__device__ __forceinline__ float sum16(float x) {
  union { float f; int i; } a, t;
  a.f = x;
  t.i = __builtin_amdgcn_update_dpp(0, a.i, 0x121, 0xF, 0xF, true); a.f += t.f;
  t.i = __builtin_amdgcn_update_dpp(0, a.i, 0x122, 0xF, 0xF, true); a.f += t.f;
  t.i = __builtin_amdgcn_update_dpp(0, a.i, 0x124, 0xF, 0xF, true); a.f += t.f;
  t.i = __builtin_amdgcn_update_dpp(0, a.i, 0x128, 0xF, 0xF, true); a.f += t.f;
  return a.f;
}

// ---------------- sentinel: ws too small ----------------
__global__ void k_sentinel(float* out, float val) {
  if (threadIdx.x < 64) out[threadIdx.x] = val;
}

// ---------------- small-vector conversion segments ----------------
struct CvtSegs {
  const void* src[10];
  unsigned short* dst[10];
  int len[10];
};

// ---- mega prep: per-block dtype probe, then cvt8 | cvt_small | trans | hist --
__global__ void k_prep(const void* __restrict__ x, unsigned short* __restrict__ x_c,
                       int n8, CvtSegs segs,
                       const void* __restrict__ s0, const void* __restrict__ s1,
                       const void* __restrict__ s2, const void* __restrict__ s3,
                       unsigned short* __restrict__ d0, unsigned short* __restrict__ d1,
                       unsigned short* __restrict__ d2, unsigned short* __restrict__ d3,
                       const int* __restrict__ edst, int* deg, int E, int N,
                       int* dflag, int* colx, int ET, int nCvt8, int nTransB) {
  __shared__ int csh;
  if (threadIdx.x == 0) csh = 0;
  __syncthreads();
  {
    unsigned short u = ((const unsigned short*)x)[threadIdx.x];
    int e = (u >> 7) & 0xFF;
    atomicAdd(&csh, (u == 0) || (e >= 100 && e <= 145));
  }
  __syncthreads();
  int isf = (csh < 240);

  int b = blockIdx.x;
  if (b < nCvt8) {
    if (!isf) return;                       // bf16 input: x used directly
    int i = b * 256 + threadIdx.x;
    if (i >= n8) return;
    const float* s = (const float*)x + (size_t)i * 8;
    ushort4 a, c;
    a.x = f2bf(s[0]); a.y = f2bf(s[1]); a.z = f2bf(s[2]); a.w = f2bf(s[3]);
    c.x = f2bf(s[4]); c.y = f2bf(s[5]); c.z = f2bf(s[6]); c.w = f2bf(s[7]);
    ((ushort4*)x_c)[i * 2] = a;
    ((ushort4*)x_c)[i * 2 + 1] = c;
    return;
  }
  b -= nCvt8;
  if (b < 10) {
    if (b == 0) {
      if (threadIdx.x == 0) dflag[0] = isf;
      if (threadIdx.x >= 240) colx[ET + (threadIdx.x - 240)] = 0;  // 16-entry pad
    }
    int i = threadIdx.x;
    if (i < segs.len[b])
      segs.dst[b][i] = isf ? f2bf(((const float*)segs.src[b])[i])
                           : ((const unsigned short*)segs.src[b])[i];
    return;
  }
  b -= 10;
  if (b < nTransB) {
    int idx = b * 256 + threadIdx.x;  // flat over 98304 elements
    const void* src; unsigned short* dst; int R, C, loc;
    if (idx < 32768)      { src = s0; dst = d0; R = 128; C = 256; loc = idx; }
    else if (idx < 65536) { src = s1; dst = d1; R = 128; C = 256; loc = idx - 32768; }
    else if (idx < 81920) { src = s2; dst = d2; R = 256; C = 64;  loc = idx - 65536; }
    else                  { src = s3; dst = d3; R = 256; C = 64;  loc = idx - 81920; }
    unsigned short u = isf ? f2bf(((const float*)src)[loc])
                           : ((const unsigned short*)src)[loc];
    int r = loc / C, cc = loc - r * C;
    dst[cc * R + r] = u;
    return;
  }
  b -= nTransB;
  // histogram: 4 edges per thread (independent atomic chains) [R8-measured]
  int base = b * 1024 + threadIdx.x;
#pragma unroll
  for (int k = 0; k < 4; ++k) {
    int e = base + k * 256;
    if (e < E) atomicAdd(&deg[iclamp(edst[e], 0, N - 1)], 1);
  }
}

// ---------------- scan stage 1: per-1024 block sums (deg+1 self-loop) -------
__global__ __launch_bounds__(1024) void k_scan1(const int* __restrict__ deg, int* bsum, int N) {
  __shared__ int sm[1024];
  int tid = threadIdx.x;
  int i = blockIdx.x * 1024 + tid;
  sm[tid] = (i < N) ? deg[i] + 1 : 0;
  __syncthreads();
  for (int off = 512; off > 0; off >>= 1) {
    if (tid < off) sm[tid] += sm[tid + off];
    __syncthreads();
  }
  if (tid == 0) bsum[blockIdx.x] = sm[0];
}

// ---- scan stage 2: Hillis-Steele + inline bsum prefix -> rowptr & cursor ----
__global__ __launch_bounds__(1024) void k_scan3(const int* __restrict__ deg,
                                                const int* __restrict__ bsum,
                                                int* rowptr, int* cursor, int N) {
  __shared__ int sm[1024];
  __shared__ int boff;
  int tid = threadIdx.x;
  if (tid == 0) {
    int r = 0;
    for (int b = 0; b < blockIdx.x; ++b) r += bsum[b];
    boff = r;
  }
  int i = blockIdx.x * 1024 + tid;
  int v = (i < N) ? deg[i] + 1 : 0;
  sm[tid] = v;
  __syncthreads();
  for (int off = 1; off < 1024; off <<= 1) {
    int t = (tid >= off) ? sm[tid - off] : 0;
    __syncthreads();
    sm[tid] += t;
    __syncthreads();
  }
  if (i < N) {
    int ex = sm[tid] - v + boff;
    rowptr[i] = ex;
    cursor[i] = ex;
    if (i == N - 1) rowptr[N] = ex + v;
  }
}

// ------ dual GEMM body, register-resident B + row loop (PF=1) ------
template <int K, int CT, int RT>
__device__ __forceinline__ void gemm2r_body(
    int bx, int by, int tid,
    const unsigned short* __restrict__ A,
    const unsigned short* __restrict__ BTl, const unsigned short* __restrict__ BTr,
    const unsigned short* __restrict__ bl, const unsigned short* __restrict__ br,
    unsigned short* __restrict__ outl, unsigned short* __restrict__ outr,
    int Nrows, int M) {
  constexpr int KI = K / 32;
  int lane = tid & 63;
  int wave = tid >> 6;
  int r = lane & 15, q = lane >> 4;
  int col0 = by * (4 * CT * 16) + wave * (CT * 16);
  int row0 = bx * (16 * RT);
  short8 Bl[KI][CT], Br[KI][CT];
#pragma unroll
  for (int t = 0; t < CT; ++t) {
    const unsigned short* bpl = BTl + (size_t)(col0 + t * 16 + r) * K + q * 8;
    const unsigned short* bpr = BTr + (size_t)(col0 + t * 16 + r) * K + q * 8;
#pragma unroll
    for (int k = 0; k < KI; ++k) {
      Bl[k][t] = *reinterpret_cast<const short8*>(bpl + k * 32);
      Br[k][t] = *reinterpret_cast<const short8*>(bpr + k * 32);
    }
  }
  float bvl[CT], bvr[CT];
#pragma unroll
  for (int t = 0; t < CT; ++t) {
    bvl[t] = bf2f(bl[col0 + t * 16 + r]);
    bvr[t] = bf2f(br[col0 + t * 16 + r]);
  }
  short8 a[KI], an[KI];
  {
    int ar0 = imin(row0 + r, Nrows - 1);
    const unsigned short* Ap = A + (size_t)ar0 * K + q * 8;
#pragma unroll
    for (int k = 0; k < KI; ++k) a[k] = *reinterpret_cast<const short8*>(Ap + k * 32);
  }
  for (int rt = 0; rt < RT; ++rt) {
    if (rt + 1 < RT) {
      int arn = imin(row0 + (rt + 1) * 16 + r, Nrows - 1);
      const unsigned short* Apn = A + (size_t)arn * K + q * 8;
#pragma unroll
      for (int k = 0; k < KI; ++k) an[k] = *reinterpret_cast<const short8*>(Apn + k * 32);
    }
    floatx4 accl[CT], accr[CT];
#pragma unroll
    for (int t = 0; t < CT; ++t) {
      accl[t] = (floatx4){0.f, 0.f, 0.f, 0.f};
      accr[t] = (floatx4){0.f, 0.f, 0.f, 0.f};
    }
#pragma unroll
    for (int k = 0; k < KI; ++k) {
#pragma unroll
      for (int t = 0; t < CT; ++t) {
        accl[t] = __builtin_amdgcn_mfma_f32_16x16x32_bf16(a[k], Bl[k][t], accl[t], 0, 0, 0);
        accr[t] = __builtin_amdgcn_mfma_f32_16x16x32_bf16(a[k], Br[k][t], accr[t], 0, 0, 0);
      }
    }
#pragma unroll
    for (int t = 0; t < CT; ++t) {
      int col = col0 + t * 16 + r;
#pragma unroll
      for (int rr = 0; rr < 4; ++rr) {
        int row = row0 + rt * 16 + q * 4 + rr;
        if (row < Nrows) {
          outl[(size_t)row * M + col] = f2bf(accl[t][rr] + bvl[t]);
          outr[(size_t)row * M + col] = f2bf(accr[t][rr] + bvr[t]);
        }
      }
    }
#pragma unroll
    for (int k = 0; k < KI; ++k) a[k] = an[k];
  }
}

// ------ phase1: INTERLEAVED layer-1 GEMM || scatter (role by block parity) ----
__global__ __launch_bounds__(256) void k_phase1(
    const unsigned short* __restrict__ A0, const unsigned short* __restrict__ A1,
    const int* __restrict__ dflag,
    const unsigned short* __restrict__ BTl, const unsigned short* __restrict__ BTr,
    const unsigned short* __restrict__ bl, const unsigned short* __restrict__ br,
    unsigned short* __restrict__ outl, unsigned short* __restrict__ outr,
    int Nrows, int M, int nG, int nS,
    const int* __restrict__ esrc, const int* __restrict__ edst,
    const int* __restrict__ rowptr, int* cursor, int* colx, int E, int N) {
  int b = blockIdx.x;
  int m2 = 2 * imin(nG, nS);
  bool isG;
  int idx;
  if (b < m2) { isG = (b & 1) == 0; idx = b >> 1; }
  else        { isG = nG > nS;      idx = imin(nG, nS) + (b - m2); }
  if (isG) {
    const unsigned short* A = dflag[0] ? A1 : A0;
    gemm2r_body<128, 2, 8>(idx >> 1, idx & 1, threadIdx.x, A, BTl, BTr, bl, br,
                           outl, outr, Nrows, M);
    return;
  }
  // scatter: 4 edges per thread (independent atomic chains)
  int ET = E + N;
  int base = idx * 1024 + threadIdx.x;
#pragma unroll
  for (int k = 0; k < 4; ++k) {
    int e = base + k * 256;
    if (e < ET) {
      if (e < E) {
        int s = iclamp(esrc[e], 0, N - 1), d = iclamp(edst[e], 0, N - 1);
        int pos = atomicAdd(&cursor[d], 1);
        colx[iclamp(pos, 0, ET - 1)] = s;
      } else {
        int i = e - E;                 // self-loop: fixed last slot, no atomic
        colx[rowptr[i + 1] - 1] = i;
      }
    }
  }
}

#define UNPACK2(u, v0, v1, v2, v3)          \
  v0 = uasf(u.x << 16); v1 = uasf(u.x & 0xffff0000u); \
  v2 = uasf(u.y << 16); v3 = uasf(u.y & 0xffff0000u);

#define SCORE(q0, q1, q2, q3, p)                             \
  p = q0 * 0.6f;                                             \
  p = fmaf(q1, 0.6f, p); p = fmaf(q2, 0.6f, p); p = fmaf(q3, 0.6f, p); \
  p = fmaf(c0, fabsf(q0), p); p = fmaf(c1, fabsf(q1), p);    \
  p = fmaf(c2, fabsf(q2), p); p = fmaf(c3, fabsf(q3), p);

// ------- layer-1 aggregation FUSED with layer-2 dual GEMM epilogue --------
// Main: one wave per dst (4 dst/block); h1 rows kept in LDS (never hit HBM).
// Tail: wave w computes col-tile w of xs2/xd2 via MFMA (A rows 4..15 are
// garbage; D-row m depends only on A-row m, so unwritten rows are harmless).
__global__ __launch_bounds__(256) void k_agg_h4(
    const int* __restrict__ rowptr, const int* __restrict__ colx,
    const unsigned short* __restrict__ xs, const unsigned short* __restrict__ xd,
    const unsigned short* __restrict__ att, const unsigned short* __restrict__ bias,
    const unsigned short* __restrict__ Wl2T, const unsigned short* __restrict__ Wr2T,
    const unsigned short* __restrict__ bl2, const unsigned short* __restrict__ br2,
    unsigned short* __restrict__ xs2, unsigned short* __restrict__ xd2, int N) {
  __shared__ unsigned short tile[16 * 264];   // stride 264: breaks 512B bank alias
  int lane = threadIdx.x & 63;
  int wid = threadIdx.x >> 6;
  int dstBase = blockIdx.x * 4;
  int dst = dstBase + wid;
  bool dvalid = dst < N;
  int off = lane << 2;
  unsigned int off2 = (unsigned int)off * 2;
  const char* xsb = (const char*)xs;
  ushort4 au = *reinterpret_cast<const ushort4*>(att + off);
  int dsafe = dvalid ? dst : 0;
  ushort4 du = *reinterpret_cast<const ushort4*>(xd + (size_t)dsafe * 256 + off);
  float a0 = bf2f(au.x), a1 = bf2f(au.y), a2 = bf2f(au.z), a3 = bf2f(au.w);
  float d0 = bf2f(du.x), d1 = bf2f(du.y), d2 = bf2f(du.z), d3 = bf2f(du.w);
  float ad0 = a0 * d0, ad1 = a1 * d1, ad2 = a2 * d2, ad3 = a3 * d3;
  float c0 = copysignf(0.4f, a0), c1 = copysignf(0.4f, a1);
  float c2 = copysignf(0.4f, a2), c3 = copysignf(0.4f, a3);
  float l = 0.f, o0 = 0.f, o1 = 0.f, o2 = 0.f, o3 = 0.f;
  int beg = 0, end = 0;
  if (dvalid) {
    beg = __builtin_amdgcn_readfirstlane(rowptr[dst]);
    end = __builtin_amdgcn_readfirstlane(rowptr[dst + 1]);
  }
  if (end > beg) {
    int p0 = colx[beg], p1 = colx[beg + 1], p2 = colx[beg + 2], p3 = colx[beg + 3];
    uint2 ua = *(const uint2*)(xsb + (((unsigned)p0 << 9) + off2));
    uint2 ub = *(const uint2*)(xsb + (((unsigned)p1 << 9) + off2));
    uint2 uc = *(const uint2*)(xsb + (((unsigned)p2 << 9) + off2));
    uint2 ud = *(const uint2*)(xsb + (((unsigned)p3 << 9) + off2));
    int q0 = 0, q1 = 0, q2 = 0, q3 = 0;
    if (beg + 4 < end) {
      q0 = colx[beg + 4]; q1 = colx[beg + 5]; q2 = colx[beg + 6]; q3 = colx[beg + 7];
    }
    for (int e = beg; e < end; e += 4) {
      uint2 na = ua, nb = ub, nc = uc, nd = ud;
      if (e + 4 < end) {       // gathers from indices loaded 2 chunks ago
        na = *(const uint2*)(xsb + (((unsigned)q0 << 9) + off2));
        nb = *(const uint2*)(xsb + (((unsigned)q1 << 9) + off2));
        nc = *(const uint2*)(xsb + (((unsigned)q2 << 9) + off2));
        nd = *(const uint2*)(xsb + (((unsigned)q3 << 9) + off2));
      }
      if (e + 8 < end) {       // indices for chunk i+2 load under compute
        q0 = colx[e + 8]; q1 = colx[e + 9]; q2 = colx[e + 10]; q3 = colx[e + 11];
      }
      float va0, va1, va2, va3, vb0, vb1, vb2, vb3;
      float vc0, vc1, vc2, vc3, vd0, vd1, vd2, vd3;
      UNPACK2(ua, va0, va1, va2, va3)
      UNPACK2(ub, vb0, vb1, vb2, vb3)
      UNPACK2(uc, vc0, vc1, vc2, vc3)
      UNPACK2(ud, vd0, vd1, vd2, vd3)
      float qa0 = fmaf(a0, va0, ad0), qa1 = fmaf(a1, va1, ad1);
      float qa2 = fmaf(a2, va2, ad2), qa3 = fmaf(a3, va3, ad3);
      float qb0 = fmaf(a0, vb0, ad0), qb1 = fmaf(a1, vb1, ad1);
      float qb2 = fmaf(a2, vb2, ad2), qb3 = fmaf(a3, vb3, ad3);
      float qc0 = fmaf(a0, vc0, ad0), qc1 = fmaf(a1, vc1, ad1);
      float qc2 = fmaf(a2, vc2, ad2), qc3 = fmaf(a3, vc3, ad3);
      float qd0 = fmaf(a0, vd0, ad0), qd1 = fmaf(a1, vd1, ad1);
      float qd2 = fmaf(a2, vd2, ad2), qd3 = fmaf(a3, vd3, ad3);
      float pa, pb, pc, pd;
      SCORE(qa0, qa1, qa2, qa3, pa)
      SCORE(qb0, qb1, qb2, qb3, pb)
      SCORE(qc0, qc1, qc2, qc3, pc)
      SCORE(qd0, qd1, qd2, qd3, pd)
      pa = sum16(pa); pb = sum16(pb); pc = sum16(pc); pd = sum16(pd);
      pa = fminf(pa, 60.f);
      pb = (e + 1 < end) ? fminf(pb, 60.f) : -INFINITY;
      pc = (e + 2 < end) ? fminf(pc, 60.f) : -INFINITY;
      pd = (e + 3 < end) ? fminf(pd, 60.f) : -INFINITY;
      float wa = __expf(pa), wb = __expf(pb), wc = __expf(pc), wd = __expf(pd);
      l += (wa + wb) + (wc + wd);
      o0 = fmaf(wa, va0, o0); o0 = fmaf(wb, vb0, o0);
      o0 = fmaf(wc, vc0, o0); o0 = fmaf(wd, vd0, o0);
      o1 = fmaf(wa, va1, o1); o1 = fmaf(wb, vb1, o1);
      o1 = fmaf(wc, vc1, o1); o1 = fmaf(wd, vd1, o1);
      o2 = fmaf(wa, va2, o2); o2 = fmaf(wb, vb2, o2);
      o2 = fmaf(wc, vc2, o2); o2 = fmaf(wd, vd2, o2);
      o3 = fmaf(wa, va3, o3); o3 = fmaf(wb, vb3, o3);
      o3 = fmaf(wc, vc3, o3); o3 = fmaf(wd, vd3, o3);
      ua = na; ub = nb; uc = nc; ud = nd;
    }
    float rl = 1.0f / l;
    ushort4 bu = *reinterpret_cast<const ushort4*>(bias + off);
    ushort4 res;
    res.x = f2bf(fmaxf(fmaf(o0, rl, bf2f(bu.x)), 0.f));
    res.y = f2bf(fmaxf(fmaf(o1, rl, bf2f(bu.y)), 0.f));
    res.z = f2bf(fmaxf(fmaf(o2, rl, bf2f(bu.z)), 0.f));
    res.w = f2bf(fmaxf(fmaf(o3, rl, bf2f(bu.w)), 0.f));
    *reinterpret_cast<ushort4*>(&tile[wid * 264 + off]) = res;   // h1 row -> LDS
  }
  __syncthreads();
  // ---- fused layer-2 dual GEMM: wave wid covers cols [wid*16, wid*16+16) ----
  {
    int r = lane & 15, q = lane >> 4;
    const unsigned short* bpl = Wl2T + (size_t)(wid * 16 + r) * 256 + q * 8;
    const unsigned short* bpr = Wr2T + (size_t)(wid * 16 + r) * 256 + q * 8;
    floatx4 accl = {0.f, 0.f, 0.f, 0.f}, accr = {0.f, 0.f, 0.f, 0.f};
    short8 af0 = *reinterpret_cast<const short8*>(&tile[r * 264 + q * 8]);
    short8 bl0 = *reinterpret_cast<const short8*>(bpl);
    short8 br0 = *reinterpret_cast<const short8*>(bpr);
#pragma unroll
    for (int k = 0; k < 8; ++k) {
      short8 af1 = af0, bl1 = bl0, br1 = br0;
      if (k < 7) {
        af1 = *reinterpret_cast<const short8*>(&tile[r * 264 + (k + 1) * 32 + q * 8]);
        bl1 = *reinterpret_cast<const short8*>(bpl + (k + 1) * 32);
        br1 = *reinterpret_cast<const short8*>(bpr + (k + 1) * 32);
      }
      accl = __builtin_amdgcn_mfma_f32_16x16x32_bf16(af0, bl0, accl, 0, 0, 0);
      accr = __builtin_amdgcn_mfma_f32_16x16x32_bf16(af0, br0, accr, 0, 0, 0);
      af0 = af1; bl0 = bl1; br0 = br1;
    }
    if (q == 0) {                 // lanes 0-15 hold D rows 0..3 (valid dst rows)
      int col = wid * 16 + r;
      float bvl = bf2f(bl2[col]);
      float bvr = bf2f(br2[col]);
#pragma unroll
      for (int rr = 0; rr < 4; ++rr) {
        int dd = dstBase + rr;
        if (dd < N) {
          xs2[(size_t)dd * 64 + col] = f2bf(accl[rr] + bvl);
          xd2[(size_t)dd * 64 + col] = f2bf(accr[rr] + bvr);
        }
      }
    }
  }
}

// ------- layer-2 aggregation: H=1, C=64, 4 dst/wave, 4-edge unroll ---------
__global__ __launch_bounds__(256) void k_agg_h1(
    const int* __restrict__ rowptr, const int* __restrict__ colx,
    const unsigned short* __restrict__ xs, const unsigned short* __restrict__ xd,
    const unsigned short* __restrict__ att, const unsigned short* __restrict__ bias,
    float* __restrict__ hout, int N) {
  int lane = threadIdx.x & 63;
  int wid = (blockIdx.x * 256 + threadIdx.x) >> 6;
  int g = lane >> 4, sl = lane & 15;
  int dst = wid * 4 + g;
  bool valid = dst < N;
  int dsafe = valid ? dst : 0;
  int cb = sl << 2;
  unsigned int cb2 = (unsigned int)cb * 2;
  const char* xsb = (const char*)xs;
  ushort4 au = *reinterpret_cast<const ushort4*>(att + cb);
  ushort4 du = *reinterpret_cast<const ushort4*>(xd + (size_t)dsafe * 64 + cb);
  float a0 = bf2f(au.x), a1 = bf2f(au.y), a2 = bf2f(au.z), a3 = bf2f(au.w);
  float d0 = bf2f(du.x), d1 = bf2f(du.y), d2 = bf2f(du.z), d3 = bf2f(du.w);
  float ad0 = a0 * d0, ad1 = a1 * d1, ad2 = a2 * d2, ad3 = a3 * d3;
  float c0 = copysignf(0.4f, a0), c1 = copysignf(0.4f, a1);
  float c2 = copysignf(0.4f, a2), c3 = copysignf(0.4f, a3);
  float l = 0.f, o0 = 0.f, o1 = 0.f, o2 = 0.f, o3 = 0.f;
  int beg = valid ? rowptr[dst] : 0;
  int end = valid ? rowptr[dst + 1] : 0;
  if (end > beg) {
    int p0 = colx[beg], p1 = colx[beg + 1], p2 = colx[beg + 2], p3 = colx[beg + 3];
    uint2 ua = *(const uint2*)(xsb + (((unsigned)p0 << 7) + cb2));
    uint2 ub = *(const uint2*)(xsb + (((unsigned)p1 << 7) + cb2));
    uint2 uc = *(const uint2*)(xsb + (((unsigned)p2 << 7) + cb2));
    uint2 ud = *(const uint2*)(xsb + (((unsigned)p3 << 7) + cb2));
    int q0 = 0, q1 = 0, q2 = 0, q3 = 0;
    if (beg + 4 < end) {
      q0 = colx[beg + 4]; q1 = colx[beg + 5]; q2 = colx[beg + 6]; q3 = colx[beg + 7];
    }
    for (int e = beg; e < end; e += 4) {
      uint2 na = ua, nb = ub, nc = uc, nd = ud;
      if (e + 4 < end) {
        na = *(const uint2*)(xsb + (((unsigned)q0 << 7) + cb2));
        nb = *(const uint2*)(xsb + (((unsigned)q1 << 7) + cb2));
        nc = *(const uint2*)(xsb + (((unsigned)q2 << 7) + cb2));
        nd = *(const uint2*)(xsb + (((unsigned)q3 << 7) + cb2));
      }
      if (e + 8 < end) {
        q0 = colx[e + 8]; q1 = colx[e + 9]; q2 = colx[e + 10]; q3 = colx[e + 11];
      }
      float va0, va1, va2, va3, vb0, vb1, vb2, vb3;
      float vc0, vc1, vc2, vc3, vd0, vd1, vd2, vd3;
      UNPACK2(ua, va0, va1, va2, va3)
      UNPACK2(ub, vb0, vb1, vb2, vb3)
      UNPACK2(uc, vc0, vc1, vc2, vc3)
      UNPACK2(ud, vd0, vd1, vd2, vd3)
      float qa0 = fmaf(a0, va0, ad0), qa1 = fmaf(a1, va1, ad1);
      float qa2 = fmaf(a2, va2, ad2), qa3 = fmaf(a3, va3, ad3);
      float qb0 = fmaf(a0, vb0, ad0), qb1 = fmaf(a1, vb1, ad1);
      float qb2 = fmaf(a2, vb2, ad2), qb3 = fmaf(a3, vb3, ad3);
      float qc0 = fmaf(a0, vc0, ad0), qc1 = fmaf(a1, vc1, ad1);
      float qc2 = fmaf(a2, vc2, ad2), qc3 = fmaf(a3, vc3, ad3);
      float qd0 = fmaf(a0, vd0, ad0), qd1 = fmaf(a1, vd1, ad1);
      float qd2 = fmaf(a2, vd2, ad2), qd3 = fmaf(a3, vd3, ad3);
      float pa, pb, pc, pd;
      SCORE(qa0, qa1, qa2, qa3, pa)
      SCORE(qb0, qb1, qb2, qb3, pb)
      SCORE(qc0, qc1, qc2, qc3, pc)
      SCORE(qd0, qd1, qd2, qd3, pd)
      pa = sum16(pa); pb = sum16(pb); pc = sum16(pc); pd = sum16(pd);
      pa = fminf(pa, 60.f);
      pb = (e + 1 < end) ? fminf(pb, 60.f) : -INFINITY;
      pc = (e + 2 < end) ? fminf(pc, 60.f) : -INFINITY;
      pd = (e + 3 < end) ? fminf(pd, 60.f) : -INFINITY;
      float wa = __expf(pa), wb = __expf(pb), wc = __expf(pc), wd = __expf(pd);
      l += (wa + wb) + (wc + wd);
      o0 = fmaf(wa, va0, o0); o0 = fmaf(wb, vb0, o0);
      o0 = fmaf(wc, vc0, o0); o0 = fmaf(wd, vd0, o0);
      o1 = fmaf(wa, va1, o1); o1 = fmaf(wb, vb1, o1);
      o1 = fmaf(wc, vc1, o1); o1 = fmaf(wd, vd1, o1);
      o2 = fmaf(wa, va2, o2); o2 = fmaf(wb, vb2, o2);
      o2 = fmaf(wc, vc2, o2); o2 = fmaf(wd, vd2, o2);
      o3 = fmaf(wa, va3, o3); o3 = fmaf(wb, vb3, o3);
      o3 = fmaf(wc, vc3, o3); o3 = fmaf(wd, vd3, o3);
      ua = na; ub = nb; uc = nc; ud = nd;
    }
  }
  if (valid) {
    float rl = 1.0f / l;
    ushort4 bu = *reinterpret_cast<const ushort4*>(bias + cb);
    floatx4 res;
    res[0] = fmaf(o0, rl, bf2f(bu.x));
    res[1] = fmaf(o1, rl, bf2f(bu.y));
    res[2] = fmaf(o2, rl, bf2f(bu.z));
    res[3] = fmaf(o3, rl, bf2f(bu.w));
    *reinterpret_cast<floatx4*>(hout + (size_t)dst * 64 + cb) = res;
  }
}

// ---------------- mean pool over sorted batch [R8-measured] ----------------
__global__ __launch_bounds__(256) void k_pool(const float* __restrict__ h2,
                                              const int* __restrict__ batch,
                                              float* pool, int* cnt, int N) {
  int lane = threadIdx.x & 63;
  int wid = (blockIdx.x * 256 + threadIdx.x) >> 6;
  int n0 = wid * 32;
  if (n0 >= N) return;
  int nend = imin(n0 + 32, N);
  float acc = 0.f;
  int c = 0;
  int gcur = iclamp(batch[n0], 0, 63);
  for (int n = n0; n < nend; ++n) {
    int gg = iclamp(batch[n], 0, 63);
    if (gg != gcur) {
      atomicAdd(&pool[gcur * 64 + lane], acc);
      if (lane == 0) atomicAdd(&cnt[gcur], c);
      acc = 0.f; c = 0; gcur = gg;
    }
    acc += h2[(size_t)n * 64 + lane];
    c++;
  }
  atomicAdd(&pool[gcur * 64 + lane], acc);
  if (lane == 0) atomicAdd(&cnt[gcur], c);
}

// ---------------- final ----------------
__global__ void k_final(const float* __restrict__ pool, const int* __restrict__ cnt,
                        const unsigned short* __restrict__ Wlinc,
                        const unsigned short* __restrict__ blinc,
                        float* __restrict__ out) {
  int g = threadIdx.x;
  if (g >= 64) return;
  float inv = 1.f / fmaxf((float)cnt[g], 1.f);
  float s = 0.f;
  for (int c = 0; c < 64; ++c) s += pool[g * 64 + c] * bf2f(Wlinc[c]);
  out[g] = fmaf(s, inv, bf2f(blinc[0]));
}

extern "C" void kernel_launch(void* const* d_in, const int* in_sizes, int n_in,
                              void* d_out, int out_size, void* d_ws, size_t ws_size,
                              hipStream_t stream) {
  const void* x     = d_in[0];
  const int*  ei    = (const int*)d_in[1];
  const int*  batch = (const int*)d_in[2];
  const void* Wl1 = d_in[3];  const void* bl1 = d_in[4];
  const void* Wr1 = d_in[5];  const void* br1 = d_in[6];
  const void* att1 = d_in[7]; const void* bias1 = d_in[8];
  const void* Wl2 = d_in[9];  const void* bl2 = d_in[10];
  const void* Wr2 = d_in[11]; const void* br2 = d_in[12];
  const void* att2 = d_in[13]; const void* bias2 = d_in[14];
  const void* Wlin = d_in[15]; const void* blin = d_in[16];
  float* out = (float*)d_out;

  const int F = 128, HC = 256, C2 = 64;
  int N = in_sizes[0] / F;
  int E = in_sizes[1] / 2;
  int ET = E + N;
  const int* esrc = ei;
  const int* edst = ei + E;

  // ---- workspace carve-up ----
  char* w = (char*)d_ws;
  auto alloc = [&](size_t bytes) {
    char* p = w;
    w += (bytes + 255) & ~(size_t)255;
    return p;
  };
  int* dflag  = (int*)alloc(4);
  int* rowptr = (int*)alloc((size_t)(N + 1) * 4);
  int* cursor = (int*)alloc((size_t)N * 4);
  int* bsum   = (int*)alloc(1024 * 4);
  int* colx   = (int*)alloc((size_t)(ET + 16) * 4);
  unsigned short* smallc = (unsigned short*)alloc(4096);
  unsigned short* Wl1T = (unsigned short*)alloc((size_t)F * HC * 2);
  unsigned short* Wr1T = (unsigned short*)alloc((size_t)F * HC * 2);
  unsigned short* Wl2T = (unsigned short*)alloc((size_t)HC * C2 * 2);
  unsigned short* Wr2T = (unsigned short*)alloc((size_t)HC * C2 * 2);
  int* deg    = (int*)alloc((size_t)N * 4);     // zero-region start
  float* pool = (float*)alloc(64 * 64 * 4);
  int* cnt    = (int*)alloc(64 * 4);            // zero-region end
  unsigned short* xs1  = (unsigned short*)alloc((size_t)N * HC * 2);
  unsigned short* xd1  = (unsigned short*)alloc((size_t)N * HC * 2);
  unsigned short* h1   = (unsigned short*)alloc((size_t)N * HC * 2);
  size_t required = (size_t)(w - (char*)d_ws);
  size_t zlen = (size_t)((char*)cnt + 256 - (char*)deg);

  // x_c uses h1's slot during prep/phase1 (dead after); fused agg writes
  // xs2/xd2 into the same slot afterwards (no alias with live xs1/xd1).
  unsigned short* x_c = h1;
  unsigned short* xs2 = h1;
  unsigned short* xd2 = h1 + (size_t)N * C2;
  float*          h2  = (float*)xd1;            // xd1 dead after agg_h4

  unsigned short* bl1c   = smallc + 0;
  unsigned short* br1c   = smallc + 256;
  unsigned short* att1c  = smallc + 512;
  unsigned short* bias1c = smallc + 768;
  unsigned short* bl2c   = smallc + 1024;
  unsigned short* br2c   = smallc + 1088;
  unsigned short* att2c  = smallc + 1152;
  unsigned short* bias2c = smallc + 1216;
  unsigned short* Wlinc  = smallc + 1280;
  unsigned short* blinc  = smallc + 1344;

  if (ws_size < required) {
    k_sentinel<<<1, 64, 0, stream>>>(out, 1000.f + (float)(ws_size >> 20));
    return;
  }

  hipMemsetAsync(deg, 0, zlen, stream);

  // ---- mega prep: probe | cvt8 | small cvts | transposes | hist(4/thread) ----
  CvtSegs segs;
  const void* ssrc[10] = {bl1, br1, att1, bias1, bl2, br2, att2, bias2, Wlin, blin};
  unsigned short* sdst[10] = {bl1c, br1c, att1c, bias1c, bl2c, br2c, att2c, bias2c, Wlinc, blinc};
  int slen[10] = {256, 256, 256, 256, 64, 64, 64, 64, 64, 1};
  for (int i = 0; i < 10; ++i) { segs.src[i] = ssrc[i]; segs.dst[i] = sdst[i]; segs.len[i] = slen[i]; }
  int n8 = N * F / 8;
  int nCvt8 = (n8 + 255) / 256;
  int nTransB = (2 * F * HC + 2 * HC * C2 + 255) / 256;
  int nHist = (E + 1023) / 1024;
  k_prep<<<nCvt8 + 10 + nTransB + nHist, 256, 0, stream>>>(
      x, x_c, n8, segs, Wl1, Wr1, Wl2, Wr2, Wl1T, Wr1T, Wl2T, Wr2T,
      edst, deg, E, N, dflag, colx, ET, nCvt8, nTransB);

  // ---- scan ----
  int nb = (N + 1023) / 1024;
  k_scan1<<<nb, 1024, 0, stream>>>(deg, bsum, N);
  k_scan3<<<nb, 1024, 0, stream>>>(deg, bsum, rowptr, cursor, N);

  // ---- phase1: interleaved layer-1 GEMM || scatter ----
  int nG = ((N + 127) / 128) * 2;
  int nS = (ET + 1023) / 1024;
  k_phase1<<<nG + nS, 256, 0, stream>>>(
      (const unsigned short*)x, x_c, dflag, Wl1T, Wr1T, bl1c, br1c, xs1, xd1,
      N, HC, nG, nS, esrc, edst, rowptr, cursor, colx, E, N);

  // ---- fused layer-1 aggregation + layer-2 dual GEMM ----
  k_agg_h4<<<(N + 3) / 4, 256, 0, stream>>>(
      rowptr, colx, xs1, xd1, att1c, bias1c, Wl2T, Wr2T, bl2c, br2c, xs2, xd2, N);

  // ---- layer 2 aggregation ----
  k_agg_h1<<<(N + 15) / 16, 256, 0, stream>>>(rowptr, colx, xs2, xd2, att2c, bias2c, h2, N);

  // ---- pool + final ----
  int pw = (N + 31) / 32;
  k_pool<<<(pw + 3) / 4, 256, 0, stream>>>(h2, batch, pool, cnt, N);
  k_final<<<1, 64, 0, stream>>>(pool, cnt, Wlinc, blinc, out);
}

// Round 16
// 331.350 us; speedup vs baseline: 1.1493x; 1.1493x over previous
//
#include <hip/hip_runtime.h>
#include <hip/hip_bf16.h>
#include <math.h>

typedef __attribute__((ext_vector_type(8))) short short8;
typedef __attribute__((ext_vector_type(4))) float floatx4;

__device__ __forceinline__ float bf2f(unsigned short u) {
  union { unsigned int i; float f; } v; v.i = ((unsigned int)u) << 16; return v.f;
}
__device__ __forceinline__ unsigned short f2bf(float f) {
  union { float f; unsigned int u; } v; v.f = f;
  unsigned int r = (v.u + 0x7fffu + ((v.u >> 16) & 1u)) >> 16;
  return (unsigned short)r;
}
__device__ __forceinline__ int imin(int a, int b) { return a < b ? a : b; }
__device__ __forceinline__ int iclamp(int v, int lo, int hi) {
  return v < lo ? lo : (v > hi ? hi : v);
}
__device__ __forceinline__ float uasf(unsigned int u) {
  union { unsigned int i; float f; } v; v.i = u; return v.f;
}
// 16-lane ring-rotation sum via DPP (pure VALU)
__device__ __forceinline__ float sum16(float x) {
  union { float f; int i; } a, t;
  a.f = x;
  t.i = __builtin_amdgcn_update_dpp(0, a.i, 0x121, 0xF, 0xF, true); a.f += t.f;
  t.i = __builtin_amdgcn_update_dpp(0, a.i, 0x122, 0xF, 0xF, true); a.f += t.f;
  t.i = __builtin_amdgcn_update_dpp(0, a.i, 0x124, 0xF, 0xF, true); a.f += t.f;
  t.i = __builtin_amdgcn_update_dpp(0, a.i, 0x128, 0xF, 0xF, true); a.f += t.f;
  return a.f;
}

// ---------------- sentinel: ws too small ----------------
__global__ void k_sentinel(float* out, float val) {
  if (threadIdx.x < 64) out[threadIdx.x] = val;
}

// ---------------- small-vector conversion segments ----------------
struct CvtSegs {
  const void* src[10];
  unsigned short* dst[10];
  int len[10];
};

// ---- mega prep: per-block dtype probe, then cvt8 | cvt_small | trans | hist --
__global__ void k_prep(const void* __restrict__ x, unsigned short* __restrict__ x_c,
                       int n8, CvtSegs segs,
                       const void* __restrict__ s0, const void* __restrict__ s1,
                       const void* __restrict__ s2, const void* __restrict__ s3,
                       unsigned short* __restrict__ d0, unsigned short* __restrict__ d1,
                       unsigned short* __restrict__ d2, unsigned short* __restrict__ d3,
                       const int* __restrict__ edst, int* deg, int E, int N,
                       int* dflag, int* colx, int ET, int nCvt8, int nTransB) {
  __shared__ int csh;
  if (threadIdx.x == 0) csh = 0;
  __syncthreads();
  {
    unsigned short u = ((const unsigned short*)x)[threadIdx.x];
    int e = (u >> 7) & 0xFF;
    atomicAdd(&csh, (u == 0) || (e >= 100 && e <= 145));
  }
  __syncthreads();
  int isf = (csh < 240);

  int b = blockIdx.x;
  if (b < nCvt8) {
    if (!isf) return;                       // bf16 input: x used directly
    int i = b * 256 + threadIdx.x;
    if (i >= n8) return;
    const float* s = (const float*)x + (size_t)i * 8;
    ushort4 a, c;
    a.x = f2bf(s[0]); a.y = f2bf(s[1]); a.z = f2bf(s[2]); a.w = f2bf(s[3]);
    c.x = f2bf(s[4]); c.y = f2bf(s[5]); c.z = f2bf(s[6]); c.w = f2bf(s[7]);
    ((ushort4*)x_c)[i * 2] = a;
    ((ushort4*)x_c)[i * 2 + 1] = c;
    return;
  }
  b -= nCvt8;
  if (b < 10) {
    if (b == 0) {
      if (threadIdx.x == 0) dflag[0] = isf;
      if (threadIdx.x >= 240) colx[ET + (threadIdx.x - 240)] = 0;  // 16-entry pad
    }
    int i = threadIdx.x;
    if (i < segs.len[b])
      segs.dst[b][i] = isf ? f2bf(((const float*)segs.src[b])[i])
                           : ((const unsigned short*)segs.src[b])[i];
    return;
  }
  b -= 10;
  if (b < nTransB) {
    int idx = b * 256 + threadIdx.x;  // flat over 98304 elements
    const void* src; unsigned short* dst; int R, C, loc;
    if (idx < 32768)      { src = s0; dst = d0; R = 128; C = 256; loc = idx; }
    else if (idx < 65536) { src = s1; dst = d1; R = 128; C = 256; loc = idx - 32768; }
    else if (idx < 81920) { src = s2; dst = d2; R = 256; C = 64;  loc = idx - 65536; }
    else                  { src = s3; dst = d3; R = 256; C = 64;  loc = idx - 81920; }
    unsigned short u = isf ? f2bf(((const float*)src)[loc])
                           : ((const unsigned short*)src)[loc];
    int r = loc / C, cc = loc - r * C;
    dst[cc * R + r] = u;
    return;
  }
  b -= nTransB;
  // histogram: 4 edges per thread (independent atomic chains) [R8-measured]
  int base = b * 1024 + threadIdx.x;
#pragma unroll
  for (int k = 0; k < 4; ++k) {
    int e = base + k * 256;
    if (e < E) atomicAdd(&deg[iclamp(edst[e], 0, N - 1)], 1);
  }
}

// ---------------- scan stage 1: per-1024 block sums (deg+1 self-loop) -------
__global__ __launch_bounds__(1024) void k_scan1(const int* __restrict__ deg, int* bsum, int N) {
  __shared__ int sm[1024];
  int tid = threadIdx.x;
  int i = blockIdx.x * 1024 + tid;
  sm[tid] = (i < N) ? deg[i] + 1 : 0;
  __syncthreads();
  for (int off = 512; off > 0; off >>= 1) {
    if (tid < off) sm[tid] += sm[tid + off];
    __syncthreads();
  }
  if (tid == 0) bsum[blockIdx.x] = sm[0];
}

// ---- scan stage 2: Hillis-Steele + inline bsum prefix -> rowptr & cursor ----
__global__ __launch_bounds__(1024) void k_scan3(const int* __restrict__ deg,
                                                const int* __restrict__ bsum,
                                                int* rowptr, int* cursor, int N) {
  __shared__ int sm[1024];
  __shared__ int boff;
  int tid = threadIdx.x;
  if (tid == 0) {
    int r = 0;
    for (int b = 0; b < blockIdx.x; ++b) r += bsum[b];
    boff = r;
  }
  int i = blockIdx.x * 1024 + tid;
  int v = (i < N) ? deg[i] + 1 : 0;
  sm[tid] = v;
  __syncthreads();
  for (int off = 1; off < 1024; off <<= 1) {
    int t = (tid >= off) ? sm[tid - off] : 0;
    __syncthreads();
    sm[tid] += t;
    __syncthreads();
  }
  if (i < N) {
    int ex = sm[tid] - v + boff;
    rowptr[i] = ex;
    cursor[i] = ex;
    if (i == N - 1) rowptr[N] = ex + v;
  }
}

// ------ dual GEMM body, register-resident B + row loop (PF=1) ------
template <int K, int CT, int RT>
__device__ __forceinline__ void gemm2r_body(
    int bx, int by, int tid,
    const unsigned short* __restrict__ A,
    const unsigned short* __restrict__ BTl, const unsigned short* __restrict__ BTr,
    const unsigned short* __restrict__ bl, const unsigned short* __restrict__ br,
    unsigned short* __restrict__ outl, unsigned short* __restrict__ outr,
    int Nrows, int M) {
  constexpr int KI = K / 32;
  int lane = tid & 63;
  int wave = tid >> 6;
  int r = lane & 15, q = lane >> 4;
  int col0 = by * (4 * CT * 16) + wave * (CT * 16);
  int row0 = bx * (16 * RT);
  short8 Bl[KI][CT], Br[KI][CT];
#pragma unroll
  for (int t = 0; t < CT; ++t) {
    const unsigned short* bpl = BTl + (size_t)(col0 + t * 16 + r) * K + q * 8;
    const unsigned short* bpr = BTr + (size_t)(col0 + t * 16 + r) * K + q * 8;
#pragma unroll
    for (int k = 0; k < KI; ++k) {
      Bl[k][t] = *reinterpret_cast<const short8*>(bpl + k * 32);
      Br[k][t] = *reinterpret_cast<const short8*>(bpr + k * 32);
    }
  }
  float bvl[CT], bvr[CT];
#pragma unroll
  for (int t = 0; t < CT; ++t) {
    bvl[t] = bf2f(bl[col0 + t * 16 + r]);
    bvr[t] = bf2f(br[col0 + t * 16 + r]);
  }
  short8 a[KI], an[KI];
  {
    int ar0 = imin(row0 + r, Nrows - 1);
    const unsigned short* Ap = A + (size_t)ar0 * K + q * 8;
#pragma unroll
    for (int k = 0; k < KI; ++k) a[k] = *reinterpret_cast<const short8*>(Ap + k * 32);
  }
  for (int rt = 0; rt < RT; ++rt) {
    if (rt + 1 < RT) {
      int arn = imin(row0 + (rt + 1) * 16 + r, Nrows - 1);
      const unsigned short* Apn = A + (size_t)arn * K + q * 8;
#pragma unroll
      for (int k = 0; k < KI; ++k) an[k] = *reinterpret_cast<const short8*>(Apn + k * 32);
    }
    floatx4 accl[CT], accr[CT];
#pragma unroll
    for (int t = 0; t < CT; ++t) {
      accl[t] = (floatx4){0.f, 0.f, 0.f, 0.f};
      accr[t] = (floatx4){0.f, 0.f, 0.f, 0.f};
    }
#pragma unroll
    for (int k = 0; k < KI; ++k) {
#pragma unroll
      for (int t = 0; t < CT; ++t) {
        accl[t] = __builtin_amdgcn_mfma_f32_16x16x32_bf16(a[k], Bl[k][t], accl[t], 0, 0, 0);
        accr[t] = __builtin_amdgcn_mfma_f32_16x16x32_bf16(a[k], Br[k][t], accr[t], 0, 0, 0);
      }
    }
#pragma unroll
    for (int t = 0; t < CT; ++t) {
      int col = col0 + t * 16 + r;
#pragma unroll
      for (int rr = 0; rr < 4; ++rr) {
        int row = row0 + rt * 16 + q * 4 + rr;
        if (row < Nrows) {
          outl[(size_t)row * M + col] = f2bf(accl[t][rr] + bvl[t]);
          outr[(size_t)row * M + col] = f2bf(accr[t][rr] + bvr[t]);
        }
      }
    }
#pragma unroll
    for (int k = 0; k < KI; ++k) a[k] = an[k];
  }
}

// ------ phase1: INTERLEAVED layer-1 GEMM || scatter (role by block parity) ----
__global__ __launch_bounds__(256) void k_phase1(
    const unsigned short* __restrict__ A0, const unsigned short* __restrict__ A1,
    const int* __restrict__ dflag,
    const unsigned short* __restrict__ BTl, const unsigned short* __restrict__ BTr,
    const unsigned short* __restrict__ bl, const unsigned short* __restrict__ br,
    unsigned short* __restrict__ outl, unsigned short* __restrict__ outr,
    int Nrows, int M, int nG, int nS,
    const int* __restrict__ esrc, const int* __restrict__ edst,
    const int* __restrict__ rowptr, int* cursor, int* colx, int E, int N) {
  int b = blockIdx.x;
  int m2 = 2 * imin(nG, nS);
  bool isG;
  int idx;
  if (b < m2) { isG = (b & 1) == 0; idx = b >> 1; }
  else        { isG = nG > nS;      idx = imin(nG, nS) + (b - m2); }
  if (isG) {
    const unsigned short* A = dflag[0] ? A1 : A0;
    gemm2r_body<128, 2, 8>(idx >> 1, idx & 1, threadIdx.x, A, BTl, BTr, bl, br,
                           outl, outr, Nrows, M);
    return;
  }
  // scatter: 4 edges per thread (independent atomic chains)
  int ET = E + N;
  int base = idx * 1024 + threadIdx.x;
#pragma unroll
  for (int k = 0; k < 4; ++k) {
    int e = base + k * 256;
    if (e < ET) {
      if (e < E) {
        int s = iclamp(esrc[e], 0, N - 1), d = iclamp(edst[e], 0, N - 1);
        int pos = atomicAdd(&cursor[d], 1);
        colx[iclamp(pos, 0, ET - 1)] = s;
      } else {
        int i = e - E;                 // self-loop: fixed last slot, no atomic
        colx[rowptr[i + 1] - 1] = i;
      }
    }
  }
}

// ---------------- layer-2 GEMM ----------------
__global__ __launch_bounds__(256) void k_gemm2r_l2(
    const unsigned short* __restrict__ A,
    const unsigned short* __restrict__ BTl, const unsigned short* __restrict__ BTr,
    const unsigned short* __restrict__ bl, const unsigned short* __restrict__ br,
    unsigned short* __restrict__ outl, unsigned short* __restrict__ outr,
    int Nrows, int M) {
  gemm2r_body<256, 1, 4>(blockIdx.x, 0, threadIdx.x, A, BTl, BTr, bl, br,
                         outl, outr, Nrows, M);
}

#define UNPACK2(u, v0, v1, v2, v3)          \
  v0 = uasf(u.x << 16); v1 = uasf(u.x & 0xffff0000u); \
  v2 = uasf(u.y << 16); v3 = uasf(u.y & 0xffff0000u);

#define SCORE(q0, q1, q2, q3, p)                             \
  p = q0 * 0.6f;                                             \
  p = fmaf(q1, 0.6f, p); p = fmaf(q2, 0.6f, p); p = fmaf(q3, 0.6f, p); \
  p = fmaf(c0, fabsf(q0), p); p = fmaf(c1, fabsf(q1), p);    \
  p = fmaf(c2, fabsf(q2), p); p = fmaf(c3, fabsf(q3), p);

// ------- layer-1 aggregation: H=4, C=64, one wave per dst, 4-edge unroll -----
// colx indices prefetched TWO chunks ahead: gathers at iteration top have no
// dependency on loads issued this iteration (breaks colx->gather chain).
__global__ __launch_bounds__(256) void k_agg_h4(
    const int* __restrict__ rowptr, const int* __restrict__ colx,
    const unsigned short* __restrict__ xs, const unsigned short* __restrict__ xd,
    const unsigned short* __restrict__ att, const unsigned short* __restrict__ bias,
    unsigned short* __restrict__ hout, int N) {
  int lane = threadIdx.x & 63;
  int dst = (blockIdx.x * 256 + threadIdx.x) >> 6;
  if (dst >= N) return;
  int off = lane << 2;
  unsigned int off2 = (unsigned int)off * 2;
  const char* xsb = (const char*)xs;
  ushort4 au = *reinterpret_cast<const ushort4*>(att + off);
  ushort4 du = *reinterpret_cast<const ushort4*>(xd + (size_t)dst * 256 + off);
  float a0 = bf2f(au.x), a1 = bf2f(au.y), a2 = bf2f(au.z), a3 = bf2f(au.w);
  float d0 = bf2f(du.x), d1 = bf2f(du.y), d2 = bf2f(du.z), d3 = bf2f(du.w);
  float ad0 = a0 * d0, ad1 = a1 * d1, ad2 = a2 * d2, ad3 = a3 * d3;
  float c0 = copysignf(0.4f, a0), c1 = copysignf(0.4f, a1);
  float c2 = copysignf(0.4f, a2), c3 = copysignf(0.4f, a3);
  float l = 0.f, o0 = 0.f, o1 = 0.f, o2 = 0.f, o3 = 0.f;
  int beg = __builtin_amdgcn_readfirstlane(rowptr[dst]);
  int end = __builtin_amdgcn_readfirstlane(rowptr[dst + 1]);
  // chunk 0 indices + gathers; chunk 1 indices (colx padded by 16: reads past
  // `end` hit next-row entries or pad zeros -> valid node indices, killed by
  // the -INF tail mask)
  int p0 = colx[beg], p1 = colx[beg + 1], p2 = colx[beg + 2], p3 = colx[beg + 3];
  uint2 ua = *(const uint2*)(xsb + (((unsigned)p0 << 9) + off2));
  uint2 ub = *(const uint2*)(xsb + (((unsigned)p1 << 9) + off2));
  uint2 uc = *(const uint2*)(xsb + (((unsigned)p2 << 9) + off2));
  uint2 ud = *(const uint2*)(xsb + (((unsigned)p3 << 9) + off2));
  int q0 = 0, q1 = 0, q2 = 0, q3 = 0;
  if (beg + 4 < end) {
    q0 = colx[beg + 4]; q1 = colx[beg + 5]; q2 = colx[beg + 6]; q3 = colx[beg + 7];
  }
  for (int e = beg; e < end; e += 4) {
    uint2 na = ua, nb = ub, nc = uc, nd = ud;
    if (e + 4 < end) {       // gathers from indices loaded 2 chunks ago
      na = *(const uint2*)(xsb + (((unsigned)q0 << 9) + off2));
      nb = *(const uint2*)(xsb + (((unsigned)q1 << 9) + off2));
      nc = *(const uint2*)(xsb + (((unsigned)q2 << 9) + off2));
      nd = *(const uint2*)(xsb + (((unsigned)q3 << 9) + off2));
    }
    if (e + 8 < end) {       // indices for chunk i+2 load under compute
      q0 = colx[e + 8]; q1 = colx[e + 9]; q2 = colx[e + 10]; q3 = colx[e + 11];
    }
    float va0, va1, va2, va3, vb0, vb1, vb2, vb3;
    float vc0, vc1, vc2, vc3, vd0, vd1, vd2, vd3;
    UNPACK2(ua, va0, va1, va2, va3)
    UNPACK2(ub, vb0, vb1, vb2, vb3)
    UNPACK2(uc, vc0, vc1, vc2, vc3)
    UNPACK2(ud, vd0, vd1, vd2, vd3)
    float qa0 = fmaf(a0, va0, ad0), qa1 = fmaf(a1, va1, ad1);
    float qa2 = fmaf(a2, va2, ad2), qa3 = fmaf(a3, va3, ad3);
    float qb0 = fmaf(a0, vb0, ad0), qb1 = fmaf(a1, vb1, ad1);
    float qb2 = fmaf(a2, vb2, ad2), qb3 = fmaf(a3, vb3, ad3);
    float qc0 = fmaf(a0, vc0, ad0), qc1 = fmaf(a1, vc1, ad1);
    float qc2 = fmaf(a2, vc2, ad2), qc3 = fmaf(a3, vc3, ad3);
    float qd0 = fmaf(a0, vd0, ad0), qd1 = fmaf(a1, vd1, ad1);
    float qd2 = fmaf(a2, vd2, ad2), qd3 = fmaf(a3, vd3, ad3);
    float pa, pb, pc, pd;
    SCORE(qa0, qa1, qa2, qa3, pa)
    SCORE(qb0, qb1, qb2, qb3, pb)
    SCORE(qc0, qc1, qc2, qc3, pc)
    SCORE(qd0, qd1, qd2, qd3, pd)
    pa = sum16(pa); pb = sum16(pb); pc = sum16(pc); pd = sum16(pd);
    pa = fminf(pa, 60.f);                              // upper clamp only
    pb = (e + 1 < end) ? fminf(pb, 60.f) : -INFINITY;
    pc = (e + 2 < end) ? fminf(pc, 60.f) : -INFINITY;
    pd = (e + 3 < end) ? fminf(pd, 60.f) : -INFINITY;
    float wa = __expf(pa), wb = __expf(pb), wc = __expf(pc), wd = __expf(pd);
    l += (wa + wb) + (wc + wd);
    o0 = fmaf(wa, va0, o0); o0 = fmaf(wb, vb0, o0);
    o0 = fmaf(wc, vc0, o0); o0 = fmaf(wd, vd0, o0);
    o1 = fmaf(wa, va1, o1); o1 = fmaf(wb, vb1, o1);
    o1 = fmaf(wc, vc1, o1); o1 = fmaf(wd, vd1, o1);
    o2 = fmaf(wa, va2, o2); o2 = fmaf(wb, vb2, o2);
    o2 = fmaf(wc, vc2, o2); o2 = fmaf(wd, vd2, o2);
    o3 = fmaf(wa, va3, o3); o3 = fmaf(wb, vb3, o3);
    o3 = fmaf(wc, vc3, o3); o3 = fmaf(wd, vd3, o3);
    ua = na; ub = nb; uc = nc; ud = nd;
  }
  float rl = 1.0f / l;
  ushort4 bu = *reinterpret_cast<const ushort4*>(bias + off);
  ushort4 res;
  res.x = f2bf(fmaxf(fmaf(o0, rl, bf2f(bu.x)), 0.f));
  res.y = f2bf(fmaxf(fmaf(o1, rl, bf2f(bu.y)), 0.f));
  res.z = f2bf(fmaxf(fmaf(o2, rl, bf2f(bu.z)), 0.f));
  res.w = f2bf(fmaxf(fmaf(o3, rl, bf2f(bu.w)), 0.f));
  *reinterpret_cast<ushort4*>(hout + (size_t)dst * 256 + off) = res;
}

// ------- layer-2 aggregation: H=1, C=64, 4 dst/wave, 4-edge unroll ---------
__global__ __launch_bounds__(256) void k_agg_h1(
    const int* __restrict__ rowptr, const int* __restrict__ colx,
    const unsigned short* __restrict__ xs, const unsigned short* __restrict__ xd,
    const unsigned short* __restrict__ att, const unsigned short* __restrict__ bias,
    float* __restrict__ hout, int N) {
  int lane = threadIdx.x & 63;
  int wid = (blockIdx.x * 256 + threadIdx.x) >> 6;
  int g = lane >> 4, sl = lane & 15;
  int dst = wid * 4 + g;
  bool valid = dst < N;
  int dsafe = valid ? dst : 0;
  int cb = sl << 2;
  unsigned int cb2 = (unsigned int)cb * 2;
  const char* xsb = (const char*)xs;
  ushort4 au = *reinterpret_cast<const ushort4*>(att + cb);
  ushort4 du = *reinterpret_cast<const ushort4*>(xd + (size_t)dsafe * 64 + cb);
  float a0 = bf2f(au.x), a1 = bf2f(au.y), a2 = bf2f(au.z), a3 = bf2f(au.w);
  float d0 = bf2f(du.x), d1 = bf2f(du.y), d2 = bf2f(du.z), d3 = bf2f(du.w);
  float ad0 = a0 * d0, ad1 = a1 * d1, ad2 = a2 * d2, ad3 = a3 * d3;
  float c0 = copysignf(0.4f, a0), c1 = copysignf(0.4f, a1);
  float c2 = copysignf(0.4f, a2), c3 = copysignf(0.4f, a3);
  float l = 0.f, o0 = 0.f, o1 = 0.f, o2 = 0.f, o3 = 0.f;
  int beg = valid ? rowptr[dst] : 0;
  int end = valid ? rowptr[dst + 1] : 0;
  if (end > beg) {
    int p0 = colx[beg], p1 = colx[beg + 1], p2 = colx[beg + 2], p3 = colx[beg + 3];
    uint2 ua = *(const uint2*)(xsb + (((unsigned)p0 << 7) + cb2));
    uint2 ub = *(const uint2*)(xsb + (((unsigned)p1 << 7) + cb2));
    uint2 uc = *(const uint2*)(xsb + (((unsigned)p2 << 7) + cb2));
    uint2 ud = *(const uint2*)(xsb + (((unsigned)p3 << 7) + cb2));
    int q0 = 0, q1 = 0, q2 = 0, q3 = 0;
    if (beg + 4 < end) {
      q0 = colx[beg + 4]; q1 = colx[beg + 5]; q2 = colx[beg + 6]; q3 = colx[beg + 7];
    }
    for (int e = beg; e < end; e += 4) {
      uint2 na = ua, nb = ub, nc = uc, nd = ud;
      if (e + 4 < end) {
        na = *(const uint2*)(xsb + (((unsigned)q0 << 7) + cb2));
        nb = *(const uint2*)(xsb + (((unsigned)q1 << 7) + cb2));
        nc = *(const uint2*)(xsb + (((unsigned)q2 << 7) + cb2));
        nd = *(const uint2*)(xsb + (((unsigned)q3 << 7) + cb2));
      }
      if (e + 8 < end) {
        q0 = colx[e + 8]; q1 = colx[e + 9]; q2 = colx[e + 10]; q3 = colx[e + 11];
      }
      float va0, va1, va2, va3, vb0, vb1, vb2, vb3;
      float vc0, vc1, vc2, vc3, vd0, vd1, vd2, vd3;
      UNPACK2(ua, va0, va1, va2, va3)
      UNPACK2(ub, vb0, vb1, vb2, vb3)
      UNPACK2(uc, vc0, vc1, vc2, vc3)
      UNPACK2(ud, vd0, vd1, vd2, vd3)
      float qa0 = fmaf(a0, va0, ad0), qa1 = fmaf(a1, va1, ad1);
      float qa2 = fmaf(a2, va2, ad2), qa3 = fmaf(a3, va3, ad3);
      float qb0 = fmaf(a0, vb0, ad0), qb1 = fmaf(a1, vb1, ad1);
      float qb2 = fmaf(a2, vb2, ad2), qb3 = fmaf(a3, vb3, ad3);
      float qc0 = fmaf(a0, vc0, ad0), qc1 = fmaf(a1, vc1, ad1);
      float qc2 = fmaf(a2, vc2, ad2), qc3 = fmaf(a3, vc3, ad3);
      float qd0 = fmaf(a0, vd0, ad0), qd1 = fmaf(a1, vd1, ad1);
      float qd2 = fmaf(a2, vd2, ad2), qd3 = fmaf(a3, vd3, ad3);
      float pa, pb, pc, pd;
      SCORE(qa0, qa1, qa2, qa3, pa)
      SCORE(qb0, qb1, qb2, qb3, pb)
      SCORE(qc0, qc1, qc2, qc3, pc)
      SCORE(qd0, qd1, qd2, qd3, pd)
      pa = sum16(pa); pb = sum16(pb); pc = sum16(pc); pd = sum16(pd);
      pa = fminf(pa, 60.f);
      pb = (e + 1 < end) ? fminf(pb, 60.f) : -INFINITY;
      pc = (e + 2 < end) ? fminf(pc, 60.f) : -INFINITY;
      pd = (e + 3 < end) ? fminf(pd, 60.f) : -INFINITY;
      float wa = __expf(pa), wb = __expf(pb), wc = __expf(pc), wd = __expf(pd);
      l += (wa + wb) + (wc + wd);
      o0 = fmaf(wa, va0, o0); o0 = fmaf(wb, vb0, o0);
      o0 = fmaf(wc, vc0, o0); o0 = fmaf(wd, vd0, o0);
      o1 = fmaf(wa, va1, o1); o1 = fmaf(wb, vb1, o1);
      o1 = fmaf(wc, vc1, o1); o1 = fmaf(wd, vd1, o1);
      o2 = fmaf(wa, va2, o2); o2 = fmaf(wb, vb2, o2);
      o2 = fmaf(wc, vc2, o2); o2 = fmaf(wd, vd2, o2);
      o3 = fmaf(wa, va3, o3); o3 = fmaf(wb, vb3, o3);
      o3 = fmaf(wc, vc3, o3); o3 = fmaf(wd, vd3, o3);
      ua = na; ub = nb; uc = nc; ud = nd;
    }
  }
  if (valid) {
    float rl = 1.0f / l;
    ushort4 bu = *reinterpret_cast<const ushort4*>(bias + cb);
    floatx4 res;
    res[0] = fmaf(o0, rl, bf2f(bu.x));
    res[1] = fmaf(o1, rl, bf2f(bu.y));
    res[2] = fmaf(o2, rl, bf2f(bu.z));
    res[3] = fmaf(o3, rl, bf2f(bu.w));
    *reinterpret_cast<floatx4*>(hout + (size_t)dst * 64 + cb) = res;
  }
}

// ---------------- mean pool over sorted batch [R8-measured] ----------------
__global__ __launch_bounds__(256) void k_pool(const float* __restrict__ h2,
                                              const int* __restrict__ batch,
                                              float* pool, int* cnt, int N) {
  int lane = threadIdx.x & 63;
  int wid = (blockIdx.x * 256 + threadIdx.x) >> 6;
  int n0 = wid * 32;
  if (n0 >= N) return;
  int nend = imin(n0 + 32, N);
  float acc = 0.f;
  int c = 0;
  int gcur = iclamp(batch[n0], 0, 63);
  for (int n = n0; n < nend; ++n) {
    int gg = iclamp(batch[n], 0, 63);
    if (gg != gcur) {
      atomicAdd(&pool[gcur * 64 + lane], acc);
      if (lane == 0) atomicAdd(&cnt[gcur], c);
      acc = 0.f; c = 0; gcur = gg;
    }
    acc += h2[(size_t)n * 64 + lane];
    c++;
  }
  atomicAdd(&pool[gcur * 64 + lane], acc);
  if (lane == 0) atomicAdd(&cnt[gcur], c);
}

// ---------------- final ----------------
__global__ void k_final(const float* __restrict__ pool, const int* __restrict__ cnt,
                        const unsigned short* __restrict__ Wlinc,
                        const unsigned short* __restrict__ blinc,
                        float* __restrict__ out) {
  int g = threadIdx.x;
  if (g >= 64) return;
  float inv = 1.f / fmaxf((float)cnt[g], 1.f);
  float s = 0.f;
  for (int c = 0; c < 64; ++c) s += pool[g * 64 + c] * bf2f(Wlinc[c]);
  out[g] = fmaf(s, inv, bf2f(blinc[0]));
}

extern "C" void kernel_launch(void* const* d_in, const int* in_sizes, int n_in,
                              void* d_out, int out_size, void* d_ws, size_t ws_size,
                              hipStream_t stream) {
  const void* x     = d_in[0];
  const int*  ei    = (const int*)d_in[1];
  const int*  batch = (const int*)d_in[2];
  const void* Wl1 = d_in[3];  const void* bl1 = d_in[4];
  const void* Wr1 = d_in[5];  const void* br1 = d_in[6];
  const void* att1 = d_in[7]; const void* bias1 = d_in[8];
  const void* Wl2 = d_in[9];  const void* bl2 = d_in[10];
  const void* Wr2 = d_in[11]; const void* br2 = d_in[12];
  const void* att2 = d_in[13]; const void* bias2 = d_in[14];
  const void* Wlin = d_in[15]; const void* blin = d_in[16];
  float* out = (float*)d_out;

  const int F = 128, HC = 256, C2 = 64;
  int N = in_sizes[0] / F;
  int E = in_sizes[1] / 2;
  int ET = E + N;
  const int* esrc = ei;
  const int* edst = ei + E;

  // ---- workspace carve-up ----
  char* w = (char*)d_ws;
  auto alloc = [&](size_t bytes) {
    char* p = w;
    w += (bytes + 255) & ~(size_t)255;
    return p;
  };
  int* dflag  = (int*)alloc(4);
  int* rowptr = (int*)alloc((size_t)(N + 1) * 4);
  int* cursor = (int*)alloc((size_t)N * 4);
  int* bsum   = (int*)alloc(1024 * 4);
  int* colx   = (int*)alloc((size_t)(ET + 16) * 4);
  unsigned short* smallc = (unsigned short*)alloc(4096);
  unsigned short* Wl1T = (unsigned short*)alloc((size_t)F * HC * 2);
  unsigned short* Wr1T = (unsigned short*)alloc((size_t)F * HC * 2);
  unsigned short* Wl2T = (unsigned short*)alloc((size_t)HC * C2 * 2);
  unsigned short* Wr2T = (unsigned short*)alloc((size_t)HC * C2 * 2);
  int* deg    = (int*)alloc((size_t)N * 4);     // zero-region start
  float* pool = (float*)alloc(64 * 64 * 4);
  int* cnt    = (int*)alloc(64 * 4);            // zero-region end
  unsigned short* xs1  = (unsigned short*)alloc((size_t)N * HC * 2);
  unsigned short* xd1  = (unsigned short*)alloc((size_t)N * HC * 2);
  unsigned short* h1   = (unsigned short*)alloc((size_t)N * HC * 2);
  size_t required = (size_t)(w - (char*)d_ws);
  size_t zlen = (size_t)((char*)cnt + 256 - (char*)deg);

  unsigned short* x_c = h1;
  unsigned short* xs2 = xs1;
  unsigned short* xd2 = xs1 + (size_t)N * C2;
  float*          h2  = (float*)xd1;

  unsigned short* bl1c   = smallc + 0;
  unsigned short* br1c   = smallc + 256;
  unsigned short* att1c  = smallc + 512;
  unsigned short* bias1c = smallc + 768;
  unsigned short* bl2c   = smallc + 1024;
  unsigned short* br2c   = smallc + 1088;
  unsigned short* att2c  = smallc + 1152;
  unsigned short* bias2c = smallc + 1216;
  unsigned short* Wlinc  = smallc + 1280;
  unsigned short* blinc  = smallc + 1344;

  if (ws_size < required) {
    k_sentinel<<<1, 64, 0, stream>>>(out, 1000.f + (float)(ws_size >> 20));
    return;
  }

  hipMemsetAsync(deg, 0, zlen, stream);

  // ---- mega prep: probe | cvt8 | small cvts | transposes | hist(4/thread) ----
  CvtSegs segs;
  const void* ssrc[10] = {bl1, br1, att1, bias1, bl2, br2, att2, bias2, Wlin, blin};
  unsigned short* sdst[10] = {bl1c, br1c, att1c, bias1c, bl2c, br2c, att2c, bias2c, Wlinc, blinc};
  int slen[10] = {256, 256, 256, 256, 64, 64, 64, 64, 64, 1};
  for (int i = 0; i < 10; ++i) { segs.src[i] = ssrc[i]; segs.dst[i] = sdst[i]; segs.len[i] = slen[i]; }
  int n8 = N * F / 8;
  int nCvt8 = (n8 + 255) / 256;
  int nTransB = (2 * F * HC + 2 * HC * C2 + 255) / 256;
  int nHist = (E + 1023) / 1024;
  k_prep<<<nCvt8 + 10 + nTransB + nHist, 256, 0, stream>>>(
      x, x_c, n8, segs, Wl1, Wr1, Wl2, Wr2, Wl1T, Wr1T, Wl2T, Wr2T,
      edst, deg, E, N, dflag, colx, ET, nCvt8, nTransB);

  // ---- scan ----
  int nb = (N + 1023) / 1024;
  k_scan1<<<nb, 1024, 0, stream>>>(deg, bsum, N);
  k_scan3<<<nb, 1024, 0, stream>>>(deg, bsum, rowptr, cursor, N);

  // ---- phase1: interleaved layer-1 GEMM || scatter ----
  int nG = ((N + 127) / 128) * 2;
  int nS = (ET + 1023) / 1024;
  k_phase1<<<nG + nS, 256, 0, stream>>>(
      (const unsigned short*)x, x_c, dflag, Wl1T, Wr1T, bl1c, br1c, xs1, xd1,
      N, HC, nG, nS, esrc, edst, rowptr, cursor, colx, E, N);

  // ---- layer 1 aggregation ----
  k_agg_h4<<<(N + 3) / 4, 256, 0, stream>>>(rowptr, colx, xs1, xd1, att1c, bias1c, h1, N);

  // ---- layer 2 ----
  k_gemm2r_l2<<<(N + 63) / 64, 256, 0, stream>>>(h1, Wl2T, Wr2T, bl2c, br2c, xs2, xd2, N, C2);
  k_agg_h1<<<(N + 15) / 16, 256, 0, stream>>>(rowptr, colx, xs2, xd2, att2c, bias2c, h2, N);

  // ---- pool + final ----
  int pw = (N + 31) / 32;
  k_pool<<<(pw + 3) / 4, 256, 0, stream>>>(h2, batch, pool, cnt, N);
  k_final<<<1, 64, 0, stream>>>(pool, cnt, Wlinc, blinc, out);
}